// Round 9
// baseline (265.490 us; speedup 1.0000x reference)
//
#include <hip/hip_runtime.h>
#include <cstdint>

// MultiHeadAttention: B=2 S=2048 D=768 H=12 dk=64, fp32 in/out, bf16 MFMA inside.
//
//   convert_in : q,k,v fp32 -> bf16 (qb,kb,vb)                    (ws)
//   convert_w  : w_q,w_k,w_v,w_o fp32 -> bf16                     (ws)
//   qkv_direct : Qh/Kh[b][h][s][64], Vt[b][h][64][t]  (bf16, ws)
//                NO LDS, NO barriers: MFMA fragments loaded directly from
//                global (b128 per lane, row=lane&15, k=quad*8+j); latency
//                hidden by TLP (no LDS/barrier coupling -- round-8 showed the
//                barrier pipeline caps at ~10% MFMA util regardless of
//                prefetch placement).
//   attn       : ctx[tok][768] = flash attention (no-max softmax) (bf16, ws)
//   o_direct   : out[tok][768] = ctx @ w_o^T + b_o                (fp32, d_out)

#define S_LEN 2048
#define NHEAD 12
#define DMODEL 768

typedef short s16x8 __attribute__((ext_vector_type(8)));
typedef float f32x4 __attribute__((ext_vector_type(4)));

#define MFMA16(a, b, c) __builtin_amdgcn_mfma_f32_16x16x32_bf16((a), (b), (c), 0, 0, 0)

__device__ __forceinline__ unsigned int pk_bf16(float a, float b) {
  unsigned int ua = __float_as_uint(a), ub = __float_as_uint(b);
  ua = (ua + 0x7FFFu + ((ua >> 16) & 1u)) >> 16;   // RNE
  ub = (ub + 0x7FFFu + ((ub >> 16) & 1u)) >> 16;
  return ua | (ub << 16);
}
__device__ __forceinline__ short bf16r(float a) {
  unsigned int ua = __float_as_uint(a);
  return (short)((ua + 0x7FFFu + ((ua >> 16) & 1u)) >> 16);
}
// pack hi16(b)<<16 | hi16(a) in ONE v_perm_b32 (trunc; bias cancelled via l)
__device__ __forceinline__ unsigned int pk_trunc(float a, float b) {
  return __builtin_amdgcn_perm(__float_as_uint(b), __float_as_uint(a), 0x07060302u);
}
__device__ __forceinline__ float bf16_floor(float a) {
  return __uint_as_float(__float_as_uint(a) & 0xFFFF0000u);
}

// ---------------------------------------------------------------------------
// q,k,v fp32 -> bf16. grid (3072, 3) x 256, float4/thread.
// ---------------------------------------------------------------------------
__global__ __launch_bounds__(256)
void convert_in(const float* __restrict__ q, const float* __restrict__ k,
                const float* __restrict__ v,
                short* __restrict__ qb, short* __restrict__ kb,
                short* __restrict__ vb) {
  const float* src = (blockIdx.y == 0) ? q : (blockIdx.y == 1) ? k : v;
  short* dst = (blockIdx.y == 0) ? qb : (blockIdx.y == 1) ? kb : vb;
  const long i = ((long)blockIdx.x * 256 + threadIdx.x) * 4;
  float4 f = *(const float4*)(src + i);
  uint2 u;
  u.x = pk_bf16(f.x, f.y);
  u.y = pk_bf16(f.z, f.w);
  *(uint2*)(dst + i) = u;
}

// ---------------------------------------------------------------------------
// Weight fp32 -> bf16 convert. grid (576, 4) x 256 threads, float4/thread.
// ---------------------------------------------------------------------------
__global__ __launch_bounds__(256)
void convert_w(const float* __restrict__ w0, const float* __restrict__ w1,
               const float* __restrict__ w2, const float* __restrict__ w3,
               short* __restrict__ o0, short* __restrict__ o1,
               short* __restrict__ o2, short* __restrict__ o3) {
  const float* src = (blockIdx.y == 0) ? w0 : (blockIdx.y == 1) ? w1
                   : (blockIdx.y == 2) ? w2 : w3;
  short* dst = (blockIdx.y == 0) ? o0 : (blockIdx.y == 1) ? o1
             : (blockIdx.y == 2) ? o2 : o3;
  const long i = ((long)blockIdx.x * 256 + threadIdx.x) * 4;
  float4 f = *(const float4*)(src + i);
  uint2 u;
  u.x = pk_bf16(f.x, f.y);
  u.y = pk_bf16(f.z, f.w);
  *(uint2*)(dst + i) = u;
}

// ---------------------------------------------------------------------------
// Direct-load 64x128 GEMM body (all bf16, no LDS, no barriers).
// C[m][n] = sum_k A[m][k]*B[n][k], K=768. 4 waves, wave tile 32m x 64n.
// Fragments loaded straight from global in MFMA layout; 24 k-steps as 12
// software-pipelined pairs with named register sets S0/S1.
// ---------------------------------------------------------------------------
__device__ __forceinline__ void gemm_direct(const short* __restrict__ Ab,
                                            const short* __restrict__ Bb,
                                            int m0, int n0, f32x4 (&acc)[2][4]) {
  constexpr int K = 768;
  const int lane = threadIdx.x & 63;
  const int w    = threadIdx.x >> 6;
  const int g    = lane >> 4;
  const int c    = lane & 15;
  const int wm   = (w & 1) * 32;
  const int wn   = (w >> 1) * 64;

#pragma unroll
  for (int i = 0; i < 2; ++i)
#pragma unroll
    for (int j = 0; j < 4; ++j) acc[i][j] = (f32x4){0.f, 0.f, 0.f, 0.f};

  // row base pointers (fragment = b128 at base + kt)
  const short* pa0 = Ab + (long)(m0 + wm + c) * K + g * 8;
  const short* pa1 = pa0 + 16 * K;
  const short* pb0 = Bb + (long)(n0 + wn + c) * K + g * 8;
  const short* pb1 = pb0 + 16 * K;
  const short* pb2 = pb0 + 32 * K;
  const short* pb3 = pb0 + 48 * K;

  s16x8 a0A, a1A, b0A, b1A, b2A, b3A;   // set S0
  s16x8 a0B, a1B, b0B, b1B, b2B, b3B;   // set S1

  auto loadS0 = [&](int kt) {
    a0A = *(const s16x8*)(pa0 + kt); a1A = *(const s16x8*)(pa1 + kt);
    b0A = *(const s16x8*)(pb0 + kt); b1A = *(const s16x8*)(pb1 + kt);
    b2A = *(const s16x8*)(pb2 + kt); b3A = *(const s16x8*)(pb3 + kt);
  };
  auto loadS1 = [&](int kt) {
    a0B = *(const s16x8*)(pa0 + kt); a1B = *(const s16x8*)(pa1 + kt);
    b0B = *(const s16x8*)(pb0 + kt); b1B = *(const s16x8*)(pb1 + kt);
    b2B = *(const s16x8*)(pb2 + kt); b3B = *(const s16x8*)(pb3 + kt);
  };
  auto mfmaS0 = [&]() {
    acc[0][0] = MFMA16(a0A, b0A, acc[0][0]);
    acc[0][1] = MFMA16(a0A, b1A, acc[0][1]);
    acc[0][2] = MFMA16(a0A, b2A, acc[0][2]);
    acc[0][3] = MFMA16(a0A, b3A, acc[0][3]);
    acc[1][0] = MFMA16(a1A, b0A, acc[1][0]);
    acc[1][1] = MFMA16(a1A, b1A, acc[1][1]);
    acc[1][2] = MFMA16(a1A, b2A, acc[1][2]);
    acc[1][3] = MFMA16(a1A, b3A, acc[1][3]);
  };
  auto mfmaS1 = [&]() {
    acc[0][0] = MFMA16(a0B, b0B, acc[0][0]);
    acc[0][1] = MFMA16(a0B, b1B, acc[0][1]);
    acc[0][2] = MFMA16(a0B, b2B, acc[0][2]);
    acc[0][3] = MFMA16(a0B, b3B, acc[0][3]);
    acc[1][0] = MFMA16(a1B, b0B, acc[1][0]);
    acc[1][1] = MFMA16(a1B, b1B, acc[1][1]);
    acc[1][2] = MFMA16(a1B, b2B, acc[1][2]);
    acc[1][3] = MFMA16(a1B, b3B, acc[1][3]);
  };

  loadS0(0);
#pragma unroll
  for (int j = 0; j < 12; ++j) {
    loadS1(j * 64 + 32);                          // odd tile
    mfmaS0();
    loadS0(j * 64 + 64 < K ? j * 64 + 64 : 0);    // even tile (last is dead)
    mfmaS1();
  }
}

// ---------------------------------------------------------------------------
// Fused QKV projection, direct-load. 1152 blocks, XCD-swizzled.
// ---------------------------------------------------------------------------
__global__ __launch_bounds__(256)
void qkv_kernel(const short* __restrict__ qb, const short* __restrict__ kb,
                const short* __restrict__ vb,
                const short* __restrict__ wq, const short* __restrict__ wk,
                const short* __restrict__ wv,
                const float* __restrict__ bq, const float* __restrict__ bk,
                const float* __restrict__ bv,
                short* __restrict__ qh, short* __restrict__ kh,
                short* __restrict__ vt) {
  const int L   = blockIdx.x;        // 0..1151
  const int xcd = L & 7;
  const int i   = L >> 3;            // 0..143
  const int nt  = i % 6;
  const int pl  = xcd * 24 + i / 6;  // 0..191 (m,z) pair
  const int z   = pl >> 6;
  const int mt  = pl & 63;
  const int m0  = mt * 64;           // token
  const int n0  = nt * 128;          // feature

  const short* A = (z == 0) ? qb : (z == 1) ? kb : vb;
  const short* B = (z == 0) ? wq : (z == 1) ? wk : wv;
  const float* bias = (z == 0) ? bq : (z == 1) ? bk : bv;

  f32x4 acc[2][4];
  gemm_direct(A, B, m0, n0, acc);

  const int lane = threadIdx.x & 63, w = threadIdx.x >> 6;
  const int g = lane >> 4, c = lane & 15;
  const int wm = (w & 1) * 32, wn = (w >> 1) * 64;

  if (z < 2) {
    short* outp = z ? kh : qh;
    const float scale = z ? 1.0f : 0.18033688011112042f;  // log2e/8
#pragma unroll
    for (int mb = 0; mb < 2; ++mb) {
#pragma unroll
      for (int nb = 0; nb < 4; ++nb) {
        const int n = n0 + wn + nb * 16 + c;
        const float bvv = bias[n];
        const int hh = n >> 6, d = n & 63;
#pragma unroll
        for (int r = 0; r < 4; ++r) {
          const int m = m0 + wm + mb * 16 + g * 4 + r;
          const int b = m >> 11, s = m & 2047;
          const float val = (acc[mb][nb][r] + bvv) * scale;
          outp[(((long)(b * NHEAD + hh) * S_LEN + s) << 6) + d] = bf16r(val);
        }
      }
    }
  } else {  // V: transposed write Vt[b][h][d][t], 4 consecutive t per lane
#pragma unroll
    for (int mb = 0; mb < 2; ++mb) {
#pragma unroll
      for (int nb = 0; nb < 4; ++nb) {
        const int n = n0 + wn + nb * 16 + c;   // feature
        const float bvv = bias[n];
        const int hh = n >> 6, d = n & 63;
        const int m_base = m0 + wm + mb * 16 + g * 4;   // token base
        const int b = m_base >> 11, t = m_base & 2047;
        uint2 ov;
        ov.x = pk_bf16(acc[mb][nb][0] + bvv, acc[mb][nb][1] + bvv);
        ov.y = pk_bf16(acc[mb][nb][2] + bvv, acc[mb][nb][3] + bvv);
        *(uint2*)(vt + ((long)(b * NHEAD + hh) * 64 + d) * S_LEN + t) = ov;
      }
    }
  }
}

// ---------------------------------------------------------------------------
// Output projection, direct-load. A = ctx (bf16), B = w_o (bf16), out fp32.
// 384 blocks, XCD-swizzled.
// ---------------------------------------------------------------------------
__global__ __launch_bounds__(256)
void o_kernel(const short* __restrict__ ctx, const short* __restrict__ wo,
              const float* __restrict__ bo, float* __restrict__ out) {
  const int L   = blockIdx.x;        // 0..383
  const int xcd = L & 7;
  const int i   = L >> 3;            // 0..47
  const int nt  = i % 6;
  const int mt  = xcd * 8 + i / 6;   // 0..63
  const int m0  = mt * 64;
  const int n0  = nt * 128;

  f32x4 acc[2][4];
  gemm_direct(ctx, wo, m0, n0, acc);

  const int lane = threadIdx.x & 63, w = threadIdx.x >> 6;
  const int g = lane >> 4, c = lane & 15;
  const int wm = (w & 1) * 32, wn = (w >> 1) * 64;
#pragma unroll
  for (int mb = 0; mb < 2; ++mb) {
#pragma unroll
    for (int nb = 0; nb < 4; ++nb) {
      const int n = n0 + wn + nb * 16 + c;
      const float bvv = bo[n];
#pragma unroll
      for (int r = 0; r < 4; ++r) {
        const int m = m0 + wm + mb * 16 + g * 4 + r;
        out[(long)m * DMODEL + n] = acc[mb][nb][r] + bvv;
      }
    }
  }
}

// ---------------------------------------------------------------------------
// Flash attention, no-max softmax (UNCHANGED from round 8 -- passed).
// ---------------------------------------------------------------------------
__global__ __launch_bounds__(256)
void attn_kernel(const short* __restrict__ Qh, const short* __restrict__ Kh,
                 const short* __restrict__ Vt, short* __restrict__ Ctx) {
  __shared__ short kbuf[2][64 * 64];      // swizzled [t][d]
  __shared__ short vbuf[2][64 * 64];      // swizzled [d][t]
  __shared__ short pbuf[4][16 * 64];      // per-wave [s][t], XOR-swizzled

  const int tid  = threadIdx.x;
  const int lane = tid & 63;
  const int w    = tid >> 6;
  const int g    = lane >> 4;
  const int c    = lane & 15;
  const int bh   = blockIdx.y;            // 0..23
  const int qs0  = blockIdx.x * 64;
  const long base = (long)bh * S_LEN * 64;
  const short* Qb = Qh + base;
  const short* Kb = Kh + base;
  const short* Vb = Vt + base;

  const long qrow = (long)(qs0 + w * 16 + c) * 64;
  const s16x8 qf0 = *(const s16x8*)(Qb + qrow + g * 8);
  const s16x8 qf1 = *(const s16x8*)(Qb + qrow + 32 + g * 8);

  f32x4 co[4];
#pragma unroll
  for (int i = 0; i < 4; ++i) co[i] = (f32x4){0.f, 0.f, 0.f, 0.f};
  float l_lane = 0.f;

  const int srow = tid >> 2;           // 0..63
  const int sq   = tid & 3;
  const int sw   = srow & 7;
  const int sg0  = ((2 * sq)     ^ sw) * 8;
  const int sg1  = ((2 * sq + 1) ^ sw) * 8;
  const int cw   = c & 7;
  const int rg0  = ((g)     ^ cw) * 8;
  const int rg1  = ((4 + g) ^ cw) * 8;

  const short* kg = Kb + (long)srow * 64 + sq * 16;     // + row*64
  const short* vg = Vb + (long)srow * S_LEN + sq * 16;  // + t

  uint4 rkA0, rkA1, rvA0, rvA1;
  uint4 rkB0, rkB1, rvB0, rvB1;
  auto fetchA = [&](long t0) {    // t0 = starting row/t (tile*64)
    rkA0 = *(const uint4*)(kg + t0 * 64);
    rkA1 = *(const uint4*)(kg + t0 * 64 + 8);
    rvA0 = *(const uint4*)(vg + t0);
    rvA1 = *(const uint4*)(vg + t0 + 8);
  };
  auto fetchB = [&](long t0) {
    rkB0 = *(const uint4*)(kg + t0 * 64);
    rkB1 = *(const uint4*)(kg + t0 * 64 + 8);
    rvB0 = *(const uint4*)(vg + t0);
    rvB1 = *(const uint4*)(vg + t0 + 8);
  };
  auto storeA = [&](short* kb2, short* vb2) {
    *(uint4*)&kb2[srow * 64 + sg0] = rkA0;
    *(uint4*)&kb2[srow * 64 + sg1] = rkA1;
    *(uint4*)&vb2[srow * 64 + sg0] = rvA0;
    *(uint4*)&vb2[srow * 64 + sg1] = rvA1;
  };
  auto storeB = [&](short* kb2, short* vb2) {
    *(uint4*)&kb2[srow * 64 + sg0] = rkB0;
    *(uint4*)&kb2[srow * 64 + sg1] = rkB1;
    *(uint4*)&vb2[srow * 64 + sg0] = rvB0;
    *(uint4*)&vb2[srow * 64 + sg1] = rvB1;
  };

  const int pr0 = c * 64 + ((g ^ cw) * 8);
  const int pr1 = c * 64 + (((4 + g) ^ cw) * 8);

  auto step = [&](const short* kb2, const short* vb2) {
    f32x4 st[4];
#pragma unroll
    for (int mb = 0; mb < 4; ++mb) {
      const s16x8 k0 = *(const s16x8*)&kb2[(mb * 16 + c) * 64 + rg0];
      const s16x8 k1 = *(const s16x8*)&kb2[(mb * 16 + c) * 64 + rg1];
      f32x4 z = (f32x4){0.f, 0.f, 0.f, 0.f};
      z = MFMA16(k0, qf0, z);
      z = MFMA16(k1, qf1, z);
      st[mb] = z;
    }
#pragma unroll
    for (int mb = 0; mb < 4; ++mb) {
      float p0 = __builtin_amdgcn_exp2f(st[mb][0]);
      float p1 = __builtin_amdgcn_exp2f(st[mb][1]);
      float p2 = __builtin_amdgcn_exp2f(st[mb][2]);
      float p3 = __builtin_amdgcn_exp2f(st[mb][3]);
      l_lane += bf16_floor(p0) + bf16_floor(p1) + bf16_floor(p2) + bf16_floor(p3);
      uint2 pw;
      pw.x = pk_trunc(p0, p1);
      pw.y = pk_trunc(p2, p3);
      const int pg = ((2 * mb + (g >> 1)) ^ cw) * 8 + (g & 1) * 4;
      *(uint2*)&pbuf[w][c * 64 + pg] = pw;
    }
    const s16x8 pb0 = *(const s16x8*)&pbuf[w][pr0];
    const s16x8 pb1 = *(const s16x8*)&pbuf[w][pr1];
#pragma unroll
    for (int db = 0; db < 4; ++db) {
      const s16x8 v0 = *(const s16x8*)&vb2[(db * 16 + c) * 64 + rg0];
      const s16x8 v1 = *(const s16x8*)&vb2[(db * 16 + c) * 64 + rg1];
      co[db] = MFMA16(v0, pb0, co[db]);
      co[db] = MFMA16(v1, pb1, co[db]);
    }
  };

  constexpr int NT = S_LEN / 64;   // 32 tiles
  fetchA(0);
  fetchB(64);
  storeA(kbuf[0], vbuf[0]);
  for (int j = 0; j < NT / 2; ++j) {
    __syncthreads();                                        // buf0 (tile 2j)
    fetchA((2 * j + 2 < NT) ? (long)(2 * j + 2) * 64 : 0);  // tile 2j+2 -> A
    step(kbuf[0], vbuf[0]);
    storeB(kbuf[1], vbuf[1]);                               // tile 2j+1 -> buf1
    __syncthreads();                                        // buf1 visible
    fetchB((2 * j + 3 < NT) ? (long)(2 * j + 3) * 64 : 0);  // tile 2j+3 -> B
    step(kbuf[1], vbuf[1]);
    storeA(kbuf[0], vbuf[0]);                               // tile 2j+2 -> buf0
  }

  float rs = l_lane;
  rs += __shfl_xor(rs, 16);
  rs += __shfl_xor(rs, 32);
  const float invl = 1.f / rs;

  const int hh = bh % NHEAD;
  const long tok = (long)(bh / NHEAD) * S_LEN + qs0 + w * 16 + c;
#pragma unroll
  for (int db = 0; db < 4; ++db) {
    uint2 ov;
    ov.x = pk_bf16(co[db][0] * invl, co[db][1] * invl);
    ov.y = pk_bf16(co[db][2] * invl, co[db][3] * invl);
    *(uint2*)(Ctx + tok * DMODEL + hh * 64 + db * 16 + g * 4) = ov;
  }
}

// ---------------------------------------------------------------------------
extern "C" void kernel_launch(void* const* d_in, const int* in_sizes, int n_in,
                              void* d_out, int out_size, void* d_ws, size_t ws_size,
                              hipStream_t stream) {
  const float* q   = (const float*)d_in[0];
  const float* k   = (const float*)d_in[1];
  const float* v   = (const float*)d_in[2];
  const float* w_q = (const float*)d_in[3];
  const float* b_q = (const float*)d_in[4];
  const float* w_k = (const float*)d_in[5];
  const float* b_k = (const float*)d_in[6];
  const float* w_v = (const float*)d_in[7];
  const float* b_v = (const float*)d_in[8];
  const float* w_o = (const float*)d_in[9];
  const float* b_o = (const float*)d_in[10];
  float* out = (float*)d_out;

  const long NELEM = (long)2 * NHEAD * S_LEN * 64;  // 3,145,728
  const long WELEM = (long)DMODEL * DMODEL;         // 589,824
  short* qh  = (short*)d_ws;
  short* kh  = qh + NELEM;
  short* vt  = kh + NELEM;
  short* wqb = vt + NELEM;
  short* wkb = wqb + WELEM;
  short* wvb = wkb + WELEM;
  short* wob = wvb + WELEM;
  short* qb  = wob + WELEM;
  short* kb  = qb + NELEM;
  short* vb  = kb + NELEM;
  short* ctx = qb;   // alias: qb dead after qkv_kernel; attn writes ctx after

  dim3 blk(256);
  convert_in<<<dim3(3072, 3), blk, 0, stream>>>(q, k, v, qb, kb, vb);
  convert_w<<<dim3(576, 4), blk, 0, stream>>>(w_q, w_k, w_v, w_o,
                                              wqb, wkb, wvb, wob);
  qkv_kernel<<<dim3(1152), blk, 0, stream>>>(qb, kb, vb, wqb, wkb, wvb,
                                             b_q, b_k, b_v, qh, kh, vt);
  attn_kernel<<<dim3(32, 24), blk, 0, stream>>>(qh, kh, vt, ctx);
  o_kernel<<<dim3(384), blk, 0, stream>>>(ctx, wob, b_o, out);
}

// Round 10
// 204.067 us; speedup vs baseline: 1.3010x; 1.3010x over previous
//
#include <hip/hip_runtime.h>
#include <cstdint>

// MultiHeadAttention: B=2 S=2048 D=768 H=12 dk=64, fp32 in/out, bf16 MFMA inside.
//
//   convert_all : q,k,v,w_q,w_k,w_v,w_o fp32 -> bf16              (ws)
//   qkv         : m97-style GEMM: global_load_lds width-16 DMA staging,
//                 single-buffered LDS, 2 barriers/iter, 128x128 tile.
//                 (rounds 4-9 showed hand-rolled VGPR pipelines plateau at
//                 ~10% MfmaUtil; the DMA structure is the HW-verified recipe)
//   attn        : ctx[tok][768] = flash attention (no-max softmax) (bf16, ws)
//   o           : 64x128-tile DMA GEMM -> fp32 d_out

#define S_LEN 2048
#define NHEAD 12
#define DMODEL 768

typedef short s16x8 __attribute__((ext_vector_type(8)));
typedef float f32x4 __attribute__((ext_vector_type(4)));

#define MFMA16(a, b, c) __builtin_amdgcn_mfma_f32_16x16x32_bf16((a), (b), (c), 0, 0, 0)

__device__ __forceinline__ void lds_dma16(void* lds, const void* g) {
  __builtin_amdgcn_global_load_lds(
      (const __attribute__((address_space(1))) unsigned int*)g,
      (__attribute__((address_space(3))) unsigned int*)lds, 16, 0, 0);
}

__device__ __forceinline__ unsigned int pk_bf16(float a, float b) {
  unsigned int ua = __float_as_uint(a), ub = __float_as_uint(b);
  ua = (ua + 0x7FFFu + ((ua >> 16) & 1u)) >> 16;   // RNE
  ub = (ub + 0x7FFFu + ((ub >> 16) & 1u)) >> 16;
  return ua | (ub << 16);
}
__device__ __forceinline__ short bf16r(float a) {
  unsigned int ua = __float_as_uint(a);
  return (short)((ua + 0x7FFFu + ((ua >> 16) & 1u)) >> 16);
}
// pack hi16(b)<<16 | hi16(a) in ONE v_perm_b32 (trunc; bias cancelled via l)
__device__ __forceinline__ unsigned int pk_trunc(float a, float b) {
  return __builtin_amdgcn_perm(__float_as_uint(b), __float_as_uint(a), 0x07060302u);
}
__device__ __forceinline__ float bf16_floor(float a) {
  return __uint_as_float(__float_as_uint(a) & 0xFFFF0000u);
}

// ---------------------------------------------------------------------------
// All fp32 -> bf16 conversions in ONE launch. 11520 blocks x 256 thr x
// float4/thr: blocks [0,9216) = q,k,v (3072 each); [9216,11520) = 4 weights
// (576 each).
// ---------------------------------------------------------------------------
__global__ __launch_bounds__(256)
void convert_all(const float* __restrict__ q, const float* __restrict__ k,
                 const float* __restrict__ v,
                 const float* __restrict__ w0, const float* __restrict__ w1,
                 const float* __restrict__ w2, const float* __restrict__ w3,
                 short* __restrict__ qb, short* __restrict__ kb,
                 short* __restrict__ vb,
                 short* __restrict__ o0, short* __restrict__ o1,
                 short* __restrict__ o2, short* __restrict__ o3) {
  int b = blockIdx.x;
  const float* src;
  short* dst;
  if (b < 9216) {
    const int s = b / 3072;
    src = (s == 0) ? q : (s == 1) ? k : v;
    dst = (s == 0) ? qb : (s == 1) ? kb : vb;
    b -= s * 3072;
  } else {
    b -= 9216;
    const int s = b / 576;
    src = (s == 0) ? w0 : (s == 1) ? w1 : (s == 2) ? w2 : w3;
    dst = (s == 0) ? o0 : (s == 1) ? o1 : (s == 2) ? o2 : o3;
    b -= s * 576;
  }
  const long i = ((long)b * 256 + threadIdx.x) * 4;
  float4 f = *(const float4*)(src + i);
  uint2 u;
  u.x = pk_bf16(f.x, f.y);
  u.y = pk_bf16(f.z, f.w);
  *(uint2*)(dst + i) = u;
}

// ---------------------------------------------------------------------------
// Fused QKV projection, m97-style. 576 blocks, XCD-swizzled.
// Tile 128x128, BK=32, 4 waves each 64x64 (acc[4][4]).
// Staging: global_load_lds x4 per wave (A 2, B 2), LDS rows of 32 shorts.
// ---------------------------------------------------------------------------
__global__ __launch_bounds__(256)
void qkv_kernel(const short* __restrict__ qb, const short* __restrict__ kb,
                const short* __restrict__ vb,
                const short* __restrict__ wq, const short* __restrict__ wk,
                const short* __restrict__ wv,
                const float* __restrict__ bq, const float* __restrict__ bk,
                const float* __restrict__ bv,
                short* __restrict__ qh, short* __restrict__ kh,
                short* __restrict__ vt) {
  constexpr int K = 768;
  __shared__ short Abuf[128 * 32];   // [row][k], 64B rows
  __shared__ short Bbuf[128 * 32];

  const int L   = blockIdx.x;        // 0..575
  const int xcd = L & 7;
  const int i   = L >> 3;            // 0..71
  const int nt  = i % 6;
  const int pl  = xcd * 12 + i / 6;  // 0..95 (m,z) pair
  const int z   = pl >> 5;           // 32 m-tiles per z
  const int mt  = pl & 31;
  const int m0  = mt * 128;          // token
  const int n0  = nt * 128;          // feature

  const short* A = (z == 0) ? qb : (z == 1) ? kb : vb;
  const short* B = (z == 0) ? wq : (z == 1) ? wk : wv;
  const float* bias = (z == 0) ? bq : (z == 1) ? bk : bv;

  const int tid  = threadIdx.x;
  const int lane = tid & 63;
  const int w    = tid >> 6;
  const int g    = lane >> 4;
  const int c    = lane & 15;
  const int wm   = (w & 1) * 64;
  const int wn   = (w >> 1) * 64;

  // DMA addressing: wave w covers rows [w*32, w*32+32), 2 insts x 16 rows.
  // lane l -> row +l/4, col (l&3)*8; LDS linear dest = base + l*16B.
  const int drow = w * 32 + (lane >> 2);
  const int dcol = (lane & 3) * 8;
  const short* Ag = A + (long)(m0 + drow) * K + dcol;
  const short* Bg = B + (long)(n0 + drow) * K + dcol;
  short* Al0 = &Abuf[w * 1024];
  short* Al1 = &Abuf[w * 1024 + 512];
  short* Bl0 = &Bbuf[w * 1024];
  short* Bl1 = &Bbuf[w * 1024 + 512];

  f32x4 acc[4][4];
#pragma unroll
  for (int a = 0; a < 4; ++a)
#pragma unroll
    for (int b2 = 0; b2 < 4; ++b2) acc[a][b2] = (f32x4){0.f, 0.f, 0.f, 0.f};

  for (int kt = 0; kt < K; kt += 32) {
    lds_dma16(Al0, Ag + kt);
    lds_dma16(Al1, Ag + (long)16 * K + kt);
    lds_dma16(Bl0, Bg + kt);
    lds_dma16(Bl1, Bg + (long)16 * K + kt);
    __syncthreads();   // vmcnt(0) drain: DMA landed

    s16x8 af[4], bf[4];
#pragma unroll
    for (int mb = 0; mb < 4; ++mb)
      af[mb] = *(const s16x8*)&Abuf[(wm + mb * 16 + c) * 32 + g * 8];
#pragma unroll
    for (int nb = 0; nb < 4; ++nb)
      bf[nb] = *(const s16x8*)&Bbuf[(wn + nb * 16 + c) * 32 + g * 8];
#pragma unroll
    for (int mb = 0; mb < 4; ++mb)
#pragma unroll
      for (int nb = 0; nb < 4; ++nb)
        acc[mb][nb] = MFMA16(af[mb], bf[nb], acc[mb][nb]);
    __syncthreads();   // safe to overwrite LDS
  }

  if (z < 2) {
    short* outp = z ? kh : qh;
    const float scale = z ? 1.0f : 0.18033688011112042f;  // log2e/8
#pragma unroll
    for (int mb = 0; mb < 4; ++mb) {
#pragma unroll
      for (int nb = 0; nb < 4; ++nb) {
        const int n = n0 + wn + nb * 16 + c;
        const float bvv = bias[n];
        const int hh = n >> 6, d = n & 63;
#pragma unroll
        for (int r = 0; r < 4; ++r) {
          const int m = m0 + wm + mb * 16 + g * 4 + r;
          const int b2 = m >> 11, s = m & 2047;
          const float val = (acc[mb][nb][r] + bvv) * scale;
          outp[(((long)(b2 * NHEAD + hh) * S_LEN + s) << 6) + d] = bf16r(val);
        }
      }
    }
  } else {  // V: transposed write Vt[b][h][d][t], 4 consecutive t per lane
#pragma unroll
    for (int mb = 0; mb < 4; ++mb) {
#pragma unroll
      for (int nb = 0; nb < 4; ++nb) {
        const int n = n0 + wn + nb * 16 + c;   // feature
        const float bvv = bias[n];
        const int hh = n >> 6, d = n & 63;
        const int m_base = m0 + wm + mb * 16 + g * 4;   // token base
        const int b2 = m_base >> 11, t = m_base & 2047;
        uint2 ov;
        ov.x = pk_bf16(acc[mb][nb][0] + bvv, acc[mb][nb][1] + bvv);
        ov.y = pk_bf16(acc[mb][nb][2] + bvv, acc[mb][nb][3] + bvv);
        *(uint2*)(vt + ((long)(b2 * NHEAD + hh) * 64 + d) * S_LEN + t) = ov;
      }
    }
  }
}

// ---------------------------------------------------------------------------
// Output projection, m97-style 64x128 tile. 384 blocks, XCD-swizzled.
// A = ctx (bf16), B = w_o (bf16), out fp32. Wave tile 32x64, acc[2][4].
// ---------------------------------------------------------------------------
__global__ __launch_bounds__(256)
void o_kernel(const short* __restrict__ ctx, const short* __restrict__ wo,
              const float* __restrict__ bo, float* __restrict__ out) {
  constexpr int K = 768;
  __shared__ short Abuf[64 * 32];
  __shared__ short Bbuf[128 * 32];

  const int L   = blockIdx.x;        // 0..383
  const int xcd = L & 7;
  const int i   = L >> 3;            // 0..47
  const int nt  = i % 6;
  const int mt  = xcd * 8 + i / 6;   // 0..63
  const int m0  = mt * 64;
  const int n0  = nt * 128;

  const int tid  = threadIdx.x;
  const int lane = tid & 63;
  const int w    = tid >> 6;
  const int g    = lane >> 4;
  const int c    = lane & 15;
  const int wm   = (w & 1) * 32;
  const int wn   = (w >> 1) * 64;

  // A: wave w covers rows [w*16, w*16+16), 1 inst. B: rows [w*32,+32), 2.
  const int arow = w * 16 + (lane >> 2);
  const int brow = w * 32 + (lane >> 2);
  const int dcol = (lane & 3) * 8;
  const short* Ag = ctx + (long)(m0 + arow) * K + dcol;
  const short* Bg = wo + (long)(n0 + brow) * K + dcol;
  short* Al = &Abuf[w * 512];
  short* Bl0 = &Bbuf[w * 1024];
  short* Bl1 = &Bbuf[w * 1024 + 512];

  f32x4 acc[2][4];
#pragma unroll
  for (int a = 0; a < 2; ++a)
#pragma unroll
    for (int b2 = 0; b2 < 4; ++b2) acc[a][b2] = (f32x4){0.f, 0.f, 0.f, 0.f};

  for (int kt = 0; kt < K; kt += 32) {
    lds_dma16(Al, Ag + kt);
    lds_dma16(Bl0, Bg + kt);
    lds_dma16(Bl1, Bg + (long)16 * K + kt);
    __syncthreads();

    s16x8 af[2], bf[4];
#pragma unroll
    for (int mb = 0; mb < 2; ++mb)
      af[mb] = *(const s16x8*)&Abuf[(wm + mb * 16 + c) * 32 + g * 8];
#pragma unroll
    for (int nb = 0; nb < 4; ++nb)
      bf[nb] = *(const s16x8*)&Bbuf[(wn + nb * 16 + c) * 32 + g * 8];
#pragma unroll
    for (int mb = 0; mb < 2; ++mb)
#pragma unroll
      for (int nb = 0; nb < 4; ++nb)
        acc[mb][nb] = MFMA16(af[mb], bf[nb], acc[mb][nb]);
    __syncthreads();
  }

#pragma unroll
  for (int mb = 0; mb < 2; ++mb) {
#pragma unroll
    for (int nb = 0; nb < 4; ++nb) {
      const int n = n0 + wn + nb * 16 + c;
      const float bvv = bo[n];
#pragma unroll
      for (int r = 0; r < 4; ++r) {
        const int m = m0 + wm + mb * 16 + g * 4 + r;
        out[(long)m * DMODEL + n] = acc[mb][nb][r] + bvv;
      }
    }
  }
}

// ---------------------------------------------------------------------------
// Flash attention, no-max softmax (UNCHANGED from round 8 -- passed twice).
// ---------------------------------------------------------------------------
__global__ __launch_bounds__(256)
void attn_kernel(const short* __restrict__ Qh, const short* __restrict__ Kh,
                 const short* __restrict__ Vt, short* __restrict__ Ctx) {
  __shared__ short kbuf[2][64 * 64];      // swizzled [t][d]
  __shared__ short vbuf[2][64 * 64];      // swizzled [d][t]
  __shared__ short pbuf[4][16 * 64];      // per-wave [s][t], XOR-swizzled

  const int tid  = threadIdx.x;
  const int lane = tid & 63;
  const int w    = tid >> 6;
  const int g    = lane >> 4;
  const int c    = lane & 15;
  const int bh   = blockIdx.y;            // 0..23
  const int qs0  = blockIdx.x * 64;
  const long base = (long)bh * S_LEN * 64;
  const short* Qb = Qh + base;
  const short* Kb = Kh + base;
  const short* Vb = Vt + base;

  const long qrow = (long)(qs0 + w * 16 + c) * 64;
  const s16x8 qf0 = *(const s16x8*)(Qb + qrow + g * 8);
  const s16x8 qf1 = *(const s16x8*)(Qb + qrow + 32 + g * 8);

  f32x4 co[4];
#pragma unroll
  for (int i = 0; i < 4; ++i) co[i] = (f32x4){0.f, 0.f, 0.f, 0.f};
  float l_lane = 0.f;

  const int srow = tid >> 2;           // 0..63
  const int sq   = tid & 3;
  const int sw   = srow & 7;
  const int sg0  = ((2 * sq)     ^ sw) * 8;
  const int sg1  = ((2 * sq + 1) ^ sw) * 8;
  const int cw   = c & 7;
  const int rg0  = ((g)     ^ cw) * 8;
  const int rg1  = ((4 + g) ^ cw) * 8;

  const short* kg = Kb + (long)srow * 64 + sq * 16;     // + row*64
  const short* vg = Vb + (long)srow * S_LEN + sq * 16;  // + t

  uint4 rkA0, rkA1, rvA0, rvA1;
  uint4 rkB0, rkB1, rvB0, rvB1;
  auto fetchA = [&](long t0) {    // t0 = starting row/t (tile*64)
    rkA0 = *(const uint4*)(kg + t0 * 64);
    rkA1 = *(const uint4*)(kg + t0 * 64 + 8);
    rvA0 = *(const uint4*)(vg + t0);
    rvA1 = *(const uint4*)(vg + t0 + 8);
  };
  auto fetchB = [&](long t0) {
    rkB0 = *(const uint4*)(kg + t0 * 64);
    rkB1 = *(const uint4*)(kg + t0 * 64 + 8);
    rvB0 = *(const uint4*)(vg + t0);
    rvB1 = *(const uint4*)(vg + t0 + 8);
  };
  auto storeA = [&](short* kb2, short* vb2) {
    *(uint4*)&kb2[srow * 64 + sg0] = rkA0;
    *(uint4*)&kb2[srow * 64 + sg1] = rkA1;
    *(uint4*)&vb2[srow * 64 + sg0] = rvA0;
    *(uint4*)&vb2[srow * 64 + sg1] = rvA1;
  };
  auto storeB = [&](short* kb2, short* vb2) {
    *(uint4*)&kb2[srow * 64 + sg0] = rkB0;
    *(uint4*)&kb2[srow * 64 + sg1] = rkB1;
    *(uint4*)&vb2[srow * 64 + sg0] = rvB0;
    *(uint4*)&vb2[srow * 64 + sg1] = rvB1;
  };

  const int pr0 = c * 64 + ((g ^ cw) * 8);
  const int pr1 = c * 64 + (((4 + g) ^ cw) * 8);

  auto step = [&](const short* kb2, const short* vb2) {
    f32x4 st[4];
#pragma unroll
    for (int mb = 0; mb < 4; ++mb) {
      const s16x8 k0 = *(const s16x8*)&kb2[(mb * 16 + c) * 64 + rg0];
      const s16x8 k1 = *(const s16x8*)&kb2[(mb * 16 + c) * 64 + rg1];
      f32x4 z = (f32x4){0.f, 0.f, 0.f, 0.f};
      z = MFMA16(k0, qf0, z);
      z = MFMA16(k1, qf1, z);
      st[mb] = z;
    }
#pragma unroll
    for (int mb = 0; mb < 4; ++mb) {
      float p0 = __builtin_amdgcn_exp2f(st[mb][0]);
      float p1 = __builtin_amdgcn_exp2f(st[mb][1]);
      float p2 = __builtin_amdgcn_exp2f(st[mb][2]);
      float p3 = __builtin_amdgcn_exp2f(st[mb][3]);
      l_lane += bf16_floor(p0) + bf16_floor(p1) + bf16_floor(p2) + bf16_floor(p3);
      uint2 pw;
      pw.x = pk_trunc(p0, p1);
      pw.y = pk_trunc(p2, p3);
      const int pg = ((2 * mb + (g >> 1)) ^ cw) * 8 + (g & 1) * 4;
      *(uint2*)&pbuf[w][c * 64 + pg] = pw;
    }
    const s16x8 pb0 = *(const s16x8*)&pbuf[w][pr0];
    const s16x8 pb1 = *(const s16x8*)&pbuf[w][pr1];
#pragma unroll
    for (int db = 0; db < 4; ++db) {
      const s16x8 v0 = *(const s16x8*)&vb2[(db * 16 + c) * 64 + rg0];
      const s16x8 v1 = *(const s16x8*)&vb2[(db * 16 + c) * 64 + rg1];
      co[db] = MFMA16(v0, pb0, co[db]);
      co[db] = MFMA16(v1, pb1, co[db]);
    }
  };

  constexpr int NT = S_LEN / 64;   // 32 tiles
  fetchA(0);
  fetchB(64);
  storeA(kbuf[0], vbuf[0]);
  for (int j = 0; j < NT / 2; ++j) {
    __syncthreads();                                        // buf0 (tile 2j)
    fetchA((2 * j + 2 < NT) ? (long)(2 * j + 2) * 64 : 0);  // tile 2j+2 -> A
    step(kbuf[0], vbuf[0]);
    storeB(kbuf[1], vbuf[1]);                               // tile 2j+1 -> buf1
    __syncthreads();                                        // buf1 visible
    fetchB((2 * j + 3 < NT) ? (long)(2 * j + 3) * 64 : 0);  // tile 2j+3 -> B
    step(kbuf[1], vbuf[1]);
    storeA(kbuf[0], vbuf[0]);                               // tile 2j+2 -> buf0
  }

  float rs = l_lane;
  rs += __shfl_xor(rs, 16);
  rs += __shfl_xor(rs, 32);
  const float invl = 1.f / rs;

  const int hh = bh % NHEAD;
  const long tok = (long)(bh / NHEAD) * S_LEN + qs0 + w * 16 + c;
#pragma unroll
  for (int db = 0; db < 4; ++db) {
    uint2 ov;
    ov.x = pk_bf16(co[db][0] * invl, co[db][1] * invl);
    ov.y = pk_bf16(co[db][2] * invl, co[db][3] * invl);
    *(uint2*)(Ctx + tok * DMODEL + hh * 64 + db * 16 + g * 4) = ov;
  }
}

// ---------------------------------------------------------------------------
extern "C" void kernel_launch(void* const* d_in, const int* in_sizes, int n_in,
                              void* d_out, int out_size, void* d_ws, size_t ws_size,
                              hipStream_t stream) {
  const float* q   = (const float*)d_in[0];
  const float* k   = (const float*)d_in[1];
  const float* v   = (const float*)d_in[2];
  const float* w_q = (const float*)d_in[3];
  const float* b_q = (const float*)d_in[4];
  const float* w_k = (const float*)d_in[5];
  const float* b_k = (const float*)d_in[6];
  const float* w_v = (const float*)d_in[7];
  const float* b_v = (const float*)d_in[8];
  const float* w_o = (const float*)d_in[9];
  const float* b_o = (const float*)d_in[10];
  float* out = (float*)d_out;

  const long NELEM = (long)2 * NHEAD * S_LEN * 64;  // 3,145,728
  const long WELEM = (long)DMODEL * DMODEL;         // 589,824
  short* qh  = (short*)d_ws;
  short* kh  = qh + NELEM;
  short* vt  = kh + NELEM;
  short* wqb = vt + NELEM;
  short* wkb = wqb + WELEM;
  short* wvb = wkb + WELEM;
  short* wob = wvb + WELEM;
  short* qb  = wob + WELEM;
  short* kb  = qb + NELEM;
  short* vb  = kb + NELEM;
  short* ctx = qb;   // alias: qb dead after qkv_kernel; attn writes ctx after

  dim3 blk(256);
  convert_all<<<dim3(11520), blk, 0, stream>>>(q, k, v, w_q, w_k, w_v, w_o,
                                               qb, kb, vb, wqb, wkb, wvb, wob);
  qkv_kernel<<<dim3(576), blk, 0, stream>>>(qb, kb, vb, wqb, wkb, wvb,
                                            b_q, b_k, b_v, qh, kh, vt);
  attn_kernel<<<dim3(32, 24), blk, 0, stream>>>(qh, kh, vt, ctx);
  o_kernel<<<dim3(384), blk, 0, stream>>>(ctx, wob, b_o, out);
}